// Round 1
// 474.789 us; speedup vs baseline: 1.2360x; 1.2360x over previous
//
#include <hip/hip_runtime.h>
#include <hip/hip_bf16.h>
#include <math.h>

#define TPB 256
#define TE  64
#define HP  72     // Hs / H0s / W1b ushort pitch (144 B row, 16B-aligned)
#define EP  40     // EFs / W0b ushort pitch (80 B row, 16B-aligned)
#define WP  72     // W2h ushort pitch
#define CP  90     // Cs ushort pitch: 45 dwords (odd) -> phase-4 reads 2-way, not 8-way
#define QC  80     // staged cols per quarter (72 real + 8 zero)

typedef float  v4f __attribute__((ext_vector_type(4)));
typedef short  s8v __attribute__((ext_vector_type(8)));
typedef float  f4v __attribute__((ext_vector_type(4)));

// ---------------------------------------------------------------------------
// ws layout (4-byte units):
//   cg[256] | counts[N] | starts[N+1] | cursor[N] | nzrank[N] | perm[E]
//   | (align4) rows[R*288]
// R = E/64 + N + 64. Partial row index: ri = nzrank[dst] + sorted_pos/64.
// ---------------------------------------------------------------------------

__device__ double dfact(int n){ double r = 1.0; for (int i = 2; i <= n; ++i) r *= (double)i; return r; }

__device__ void build_u(int l, double ur[5][5], double ui[5][5]){
  for (int i = 0; i < 5; ++i) for (int j = 0; j < 5; ++j){ ur[i][j] = 0.0; ui[i][j] = 0.0; }
  ur[l][l] = 1.0;
  double s = 1.0 / sqrt(2.0);
  for (int m = 1; m <= l; ++m){
    double sg = (m & 1) ? -1.0 : 1.0;
    ur[l + m][l + m] = sg * s;
    ur[l + m][l - m] = s;
    ui[l - m][l - m] = s;
    ui[l - m][l + m] = -sg * s;
  }
}

// One thread per CG output element (245). Re/im choice = parity rule.
__device__ void cg_compute(int tid, float* __restrict__ cg){
  if (tid >= 245) return;
  const int L1[9]  = {0,0,0,1,1,1,1,1,1};
  const int L2[9]  = {0,1,2,0,1,1,1,2,2};
  const int L3[9]  = {0,1,2,1,0,1,2,1,2};
  const int OFF[10] = {0,1,10,35,44,53,80,125,170,245};
  int p = 0;
  while (p < 8 && tid >= OFF[p+1]) ++p;
  int idx = tid - OFF[p];
  int l1 = L1[p], l2 = L2[p], l3 = L3[p];
  int n1 = 2*l1+1, n2 = 2*l2+1, n3 = 2*l3+1;
  int c = idx % n3; int ab = idx / n3; int b = ab % n2; int a = ab / n2;

  double Cc[5][5][5];
  for (int i = 0; i < 5; ++i) for (int j = 0; j < 5; ++j) for (int k = 0; k < 5; ++k) Cc[i][j][k] = 0.0;
  for (int m1 = -l1; m1 <= l1; ++m1) for (int m2 = -l2; m2 <= l2; ++m2){
    int m3 = m1 + m2;
    if (m3 < -l3 || m3 > l3) continue;
    double pref = sqrt((double)(2*l3+1) * dfact(l1+l2-l3) * dfact(l1-l2+l3) * dfact(-l1+l2+l3) / dfact(l1+l2+l3+1));
    pref *= sqrt(dfact(l3+m3)*dfact(l3-m3)*dfact(l1-m1)*dfact(l1+m1)*dfact(l2-m2)*dfact(l2+m2));
    double s = 0.0;
    for (int k = 0; k <= l1 + l2 - l3; ++k){
      int a0 = k, a1 = l1+l2-l3-k, a2 = l1-m1-k, a3 = l2+m2-k, a4 = l3-l2+m1+k, a5 = l3-l1-m2+k;
      if (a0 < 0 || a1 < 0 || a2 < 0 || a3 < 0 || a4 < 0 || a5 < 0) continue;
      double dd = dfact(a0)*dfact(a1)*dfact(a2)*dfact(a3)*dfact(a4)*dfact(a5);
      s += ((k & 1) ? -1.0 : 1.0) / dd;
    }
    Cc[m1+l1][m2+l2][m3+l3] = pref * s;
  }

  double U1r[5][5], U1i[5][5], U2r[5][5], U2i[5][5], U3r[5][5], U3i[5][5];
  build_u(l1, U1r, U1i); build_u(l2, U2r, U2i); build_u(l3, U3r, U3i);

  double sr = 0.0, si = 0.0;
  for (int m = 0; m < n1; ++m) for (int n = 0; n < n2; ++n) for (int o = 0; o < n3; ++o){
    double cc = Cc[m][n][o];
    if (cc == 0.0) continue;
    double xre = U1r[a][m], xim = U1i[a][m];
    double yre = U2r[b][n], yim = U2i[b][n];
    double zr = xre*yre - xim*yim, zi = xre*yim + xim*yre;
    double wr = U3r[c][o], wi = -U3i[c][o];
    double pr = zr*wr - zi*wi, pi = zr*wi + zi*wr;
    sr += pr * cc; si += pi * cc;
  }
  int use_re = (((l1 + l2 + l3) & 1) == 0);
  cg[tid] = (float)(use_re ? sr : si);
}

__global__ void cg_init_kernel(float* __restrict__ cg){
  cg_compute(threadIdx.x, cg);
}

// ---------------- CSR build (hist fused with cg) ----------------

__global__ void hist_cg_kernel(const int* __restrict__ ei, int* __restrict__ counts,
                               int E, float* __restrict__ cg, int nb){
  if ((int)blockIdx.x == nb){
    cg_compute(threadIdx.x, cg);
    return;
  }
  int e = blockIdx.x * TPB + threadIdx.x;
  if (e < E) atomicAdd(&counts[ei[2*e + 1]], 1);
}

__global__ void scan_kernel(const int* __restrict__ counts, int* __restrict__ starts,
                            int* __restrict__ cursor, int* __restrict__ nzrank, int N){
  __shared__ int part[1024];
  __shared__ int pnz[1024];
  int t = threadIdx.x;
  int T = (N + 1023) >> 10;
  int base = t * T;
  int s = 0, z = 0;
  for (int i = 0; i < T; ++i){
    int idx = base + i;
    if (idx < N){ int cc = counts[idx]; s += cc; z += (cc > 0); }
  }
  part[t] = s; pnz[t] = z; __syncthreads();
  for (int off = 1; off < 1024; off <<= 1){
    int v = (t >= off) ? part[t - off] : 0;
    int w = (t >= off) ? pnz[t - off] : 0;
    __syncthreads();
    part[t] += v; pnz[t] += w;
    __syncthreads();
  }
  int excl = (t == 0) ? 0 : part[t - 1];
  int enz  = (t == 0) ? 0 : pnz[t - 1];
  for (int i = 0; i < T; ++i){
    int idx = base + i;
    if (idx < N){
      starts[idx] = excl; cursor[idx] = excl; nzrank[idx] = enz;
      int cc = counts[idx];
      excl += cc; enz += (cc > 0);
    }
  }
  if (t == 1023) starts[N] = part[1023];
}

__global__ void perm_kernel(const int* __restrict__ ei, int* __restrict__ cursor,
                            int* __restrict__ perm, int E){
  int e = blockIdx.x * TPB + threadIdx.x;
  if (e < E){
    int pos = atomicAdd(&cursor[ei[2*e + 1]], 1);
    perm[pos] = e;
  }
}

// ---------------- helpers ----------------

__device__ __forceinline__ float silu_f(float x){
  float t = __expf(-x);
  return x * __builtin_amdgcn_rcpf(1.0f + t);
}

__device__ __forceinline__ ushort f2bf(float x){
  __hip_bfloat16 h = __float2bfloat16(x);   // RNE
  return *reinterpret_cast<ushort*>(&h);
}

__device__ __forceinline__ float bf2f(ushort u){
  uint v = (uint)u << 16;
  union { uint i; float f; } c; c.i = v;
  return c.f;
}

#define SEGSUM(v) { float _o; \
  _o = __shfl_up(v, 1);  v += samef[0]*_o; \
  _o = __shfl_up(v, 2);  v += samef[1]*_o; \
  _o = __shfl_up(v, 4);  v += samef[2]*_o; \
  _o = __shfl_up(v, 8);  v += samef[3]*_o; \
  _o = __shfl_up(v, 16); v += samef[4]*_o; \
  _o = __shfl_up(v, 32); v += samef[5]*_o; }

// ---------------------------------------------------------------------------
// Block-cooperative MFMA kernel. ALL THREE MLP GEMMs now run on the matrix
// pipe (bf16 in / fp32 accum):
//   prologue: stage ef-tile (K 16->32 zero-pad), W0^T, W1^T as bf16 in LDS
//             (aliased inside the 32256 B main-loop footprint -> occupancy
//             unchanged); layer0 MFMA -> silu -> H0s; layer1 MFMA -> silu ->
//             Hs.  W2 quarter-0 global loads issued at kernel top into regs
//             (T14 split), LDS-written after the prologue.
//   loop h=0..3: MFMA (5 tiles x 2 ksteps) -> Cs bf16 (pitch 90: odd dword
//             stride kills the old 8-way phase-4 read conflict); phase4 on
//             2 u per wave; stage next W2 quarter during phase4 epoch.
// USE_ROWS: tails write partials to rows[] with plain stores; else atomics.
// ---------------------------------------------------------------------------
template<bool USE_ROWS>
__global__ void __launch_bounds__(TPB, 4) tfn_mfma_kernel(
    const float* __restrict__ nf, const float* __restrict__ ef,
    const float* __restrict__ ev, const int* __restrict__ ei,
    const float* __restrict__ W0, const float* __restrict__ W1,
    const float* __restrict__ W2, const float* __restrict__ cg,
    const int* __restrict__ perm, const int* __restrict__ nzrank,
    float* __restrict__ rows, float* __restrict__ out, int E)
{
  // One 32256 B arena, aliased between prologue and main loop.
  //   main:     Hs[0,9216) | W2h[9216,20736) | Cs[20736,32256)
  //   prologue: EFs[0,5120) | W0b[5120,10240) | H0s[10240,19456) | W1b[19456,28672)
  // Hazard order: {EFs,W0b,W1b} -> sync -> layer0 writes H0s -> sync ->
  // layer1 reads {H0s,W1b} writes Hs (over dead EFs/W0b) -> sync ->
  // W2h write (over dead W0b-tail/H0s/W1b-head); Cs (over dead W1b-tail)
  // first written inside the h-loop after another sync.
  __shared__ char ldsb[32256];
  ushort* Hs  = (ushort*)(ldsb);
  ushort* W2h = (ushort*)(ldsb + 9216);
  ushort* Cs  = (ushort*)(ldsb + 20736);
  ushort* EFs = (ushort*)(ldsb);
  ushort* W0b = (ushort*)(ldsb + 5120);
  ushort* H0s = (ushort*)(ldsb + 10240);
  ushort* W1b = (ushort*)(ldsb + 19456);

  const int tid  = threadIdx.x;
  const int el   = tid & 63;
  const int wq   = tid >> 6;
  const int lane = el;

  int t = blockIdx.x * TE + el;
  bool valid = (t < E);
  int e = perm[valid ? t : (E - 1)];
  int d = valid ? ei[2*e + 1] : -1;
  int src = ei[2*e];

  float samef[6];
  #pragma unroll
  for (int s = 0; s < 6; ++s){
    int off = 1 << s;
    int od = __shfl_up(d, off);
    samef[s] = (lane >= off && od == d) ? 1.0f : 0.0f;
  }
  int nd = __shfl_down(d, 1);
  bool tail = valid && ((lane == 63) || (nd != d));

  int ri = 0;
  if (USE_ROWS) ri = (d >= 0 ? nzrank[d] : 0) + (t >> 6);

  // ---- T14: issue W2 quarter-0 loads early; LDS-write after prologue ----
  float regw2[20];
  #pragma unroll
  for (int m = 0; m < 20; ++m){
    int flat = m * TPB + tid;
    int col  = flat % QC;
    int k    = flat / QC;
    int p    = col >> 3, uu = col & 7;
    regw2[m] = (p < 9) ? W2[k * 288 + p * 32 + uu] : 0.f;
  }

  // ================= Prologue staging (bf16) =================
  {
    // ef tile: thread (el,wq) stages its 4-float quarter; pad k 16..32 = 0
    const v4f efv = *(const v4f*)(ef + (size_t)e * 16 + wq * 4);
    uint p0 = (uint)f2bf(efv.x) | ((uint)f2bf(efv.y) << 16);
    uint p1 = (uint)f2bf(efv.z) | ((uint)f2bf(efv.w) << 16);
    *(uint*)&EFs[el * EP + wq * 4]          = p0;
    *(uint*)&EFs[el * EP + wq * 4 + 2]      = p1;
    *(uint*)&EFs[el * EP + 16 + wq * 4]     = 0u;
    *(uint*)&EFs[el * EP + 16 + wq * 4 + 2] = 0u;
  }
  {
    // W0^T [col][k], k padded to 32 (coalesced: lanes sweep cols per k-row)
    #pragma unroll
    for (int kk = 0; kk < 8; ++kk){
      int k = wq * 8 + kk;
      float v = (k < 16) ? W0[k * 64 + el] : 0.f;
      W0b[el * EP + k] = f2bf(v);
    }
  }
  {
    // W1^T [col][k]
    #pragma unroll
    for (int kk = 0; kk < 16; ++kk){
      int k = wq * 16 + kk;
      W1b[el * HP + k] = f2bf(W1[k * 64 + el]);
    }
  }
  __syncthreads();

  const int r = lane & 15, q = lane >> 4;
  const int rowbase = wq * 16;

  // ---- layer 0 on MFMA: (64x16 ef) @ (16x64 W0), K zero-padded to 32 ----
  {
    s8v a = *(const s8v*)&EFs[(rowbase + r) * EP + q * 8];
    #pragma unroll
    for (int tt = 0; tt < 4; ++tt){
      f4v acc = {0.f, 0.f, 0.f, 0.f};
      s8v b = *(const s8v*)&W0b[(tt*16 + r) * EP + q * 8];
      acc = __builtin_amdgcn_mfma_f32_16x16x32_bf16(a, b, acc, 0, 0, 0);
      #pragma unroll
      for (int rr = 0; rr < 4; ++rr)
        H0s[(rowbase + q*4 + rr) * HP + tt*16 + r] = f2bf(silu_f(acc[rr]));
    }
  }
  __syncthreads();

  // ---- layer 1 on MFMA: (64x64 H0) @ (64x64 W1) ----
  {
    s8v a0 = *(const s8v*)&H0s[(rowbase + r) * HP + q * 8];
    s8v a1 = *(const s8v*)&H0s[(rowbase + r) * HP + 32 + q * 8];
    #pragma unroll
    for (int tt = 0; tt < 4; ++tt){
      f4v acc = {0.f, 0.f, 0.f, 0.f};
      s8v b0 = *(const s8v*)&W1b[(tt*16 + r) * HP + q * 8];
      s8v b1 = *(const s8v*)&W1b[(tt*16 + r) * HP + 32 + q * 8];
      acc = __builtin_amdgcn_mfma_f32_16x16x32_bf16(a0, b0, acc, 0, 0, 0);
      acc = __builtin_amdgcn_mfma_f32_16x16x32_bf16(a1, b1, acc, 0, 0, 0);
      #pragma unroll
      for (int rr = 0; rr < 4; ++rr)
        Hs[(rowbase + q*4 + rr) * HP + tt*16 + r] = f2bf(silu_f(acc[rr]));
    }
  }
  __syncthreads();

  // ---- write staged W2 quarter 0 (region now dead) ----
  #pragma unroll
  for (int m = 0; m < 20; ++m){
    int flat = m * TPB + tid;
    int col  = flat % QC;
    int k    = flat / QC;
    W2h[col * WP + k] = f2bf(regw2[m]);
  }

  // ---- spherical harmonics + Y-contracted CG ----
  float ex = ev[(size_t)e*3+0], eyv = ev[(size_t)e*3+1], ezv = ev[(size_t)e*3+2];
  float ri2 = __builtin_amdgcn_rcpf(sqrtf(ex*ex + eyv*eyv + ezv*ezv) + 1e-12f);
  float X = ex*ri2, Y = eyv*ri2, Z = ezv*ri2;
  const float s3 = 1.7320508075688772f;
  float Y1v[3] = {Y, Z, X};
  float Y2v[5] = {s3*X*Y, s3*Y*Z, 0.5f*(3.f*Z*Z - 1.f), s3*X*Z, 0.5f*s3*(X*X - Y*Y)};

  float B0 = cg[0];
  float B1[3], B2[5], B3[9], B4[3], B5[9], B6[15], B7[9], B8[15];
  #pragma unroll
  for (int c = 0; c < 3; ++c){ float s = 0.f;
    #pragma unroll
    for (int b = 0; b < 3; ++b) s += cg[1 + b*3 + c] * Y1v[b];
    B1[c] = s; }
  #pragma unroll
  for (int c = 0; c < 5; ++c){ float s = 0.f;
    #pragma unroll
    for (int b = 0; b < 5; ++b) s += cg[10 + b*5 + c] * Y2v[b];
    B2[c] = s; }
  #pragma unroll
  for (int i = 0; i < 9; ++i) B3[i] = cg[35 + i];
  #pragma unroll
  for (int a = 0; a < 3; ++a){ float s = 0.f;
    #pragma unroll
    for (int b = 0; b < 3; ++b) s += cg[44 + a*3 + b] * Y1v[b];
    B4[a] = s; }
  #pragma unroll
  for (int a = 0; a < 3; ++a)
    #pragma unroll
    for (int c = 0; c < 3; ++c){ float s = 0.f;
      #pragma unroll
      for (int b = 0; b < 3; ++b) s += cg[53 + (a*3 + b)*3 + c] * Y1v[b];
      B5[a*3 + c] = s; }
  #pragma unroll
  for (int a = 0; a < 3; ++a)
    #pragma unroll
    for (int c = 0; c < 5; ++c){ float s = 0.f;
      #pragma unroll
      for (int b = 0; b < 3; ++b) s += cg[80 + (a*3 + b)*5 + c] * Y1v[b];
      B6[a*5 + c] = s; }
  #pragma unroll
  for (int a = 0; a < 3; ++a)
    #pragma unroll
    for (int c = 0; c < 3; ++c){ float s = 0.f;
      #pragma unroll
      for (int b = 0; b < 5; ++b) s += cg[125 + (a*5 + b)*3 + c] * Y2v[b];
      B7[a*3 + c] = s; }
  #pragma unroll
  for (int a = 0; a < 3; ++a)
    #pragma unroll
    for (int c = 0; c < 5; ++c){ float s = 0.f;
      #pragma unroll
      for (int b = 0; b < 5; ++b) s += cg[170 + (a*5 + b)*5 + c] * Y2v[b];
      B8[a*5 + c] = s; }

  const float* xr = nf + (size_t)src * 128;
  float* dstrow = USE_ROWS ? (rows + (size_t)ri * 288)
                           : (out + (size_t)(d < 0 ? 0 : d) * 288);

  #pragma unroll 1
  for (int h = 0; h < 4; ++h){
    __syncthreads();   // W2h(quarter h) ready; Cs consumed

    // ============== MFMA: 5 col-tiles x 2 k-steps ==============
    s8v ha0 = *(const s8v*)&Hs[(rowbase + r) * HP + q * 8];
    s8v ha1 = *(const s8v*)&Hs[(rowbase + r) * HP + 32 + q * 8];
    #pragma unroll 1
    for (int tt = 0; tt < 5; ++tt){
      f4v acc4 = {0.f, 0.f, 0.f, 0.f};
      s8v b0 = *(const s8v*)&W2h[(tt*16 + r) * WP + q * 8];
      s8v b1 = *(const s8v*)&W2h[(tt*16 + r) * WP + 32 + q * 8];
      acc4 = __builtin_amdgcn_mfma_f32_16x16x32_bf16(ha0, b0, acc4, 0, 0, 0);
      acc4 = __builtin_amdgcn_mfma_f32_16x16x32_bf16(ha1, b1, acc4, 0, 0, 0);
      #pragma unroll
      for (int rr = 0; rr < 4; ++rr)
        Cs[(rowbase + q*4 + rr) * CP + tt*16 + r] = f2bf(acc4[rr]);
    }

    __syncthreads();   // Cs ready; W2h consumed

    // ============== Phase 4: silu + tensor + segmented scatter ==============
    #pragma unroll 1
    for (int j = 0; j < 2; ++j){
      int uuq = wq * 2 + j;        // 0..7 within quarter
      int u   = h * 8 + uuq;       // global channel

      float wvj[9];
      #pragma unroll
      for (int p = 0; p < 9; ++p) wvj[p] = silu_f(bf2f(Cs[el * CP + p*8 + uuq]));

      float x0 = xr[u];
      float xa = xr[32 + 3*u + 0], xb = xr[32 + 3*u + 1], xc = xr[32 + 3*u + 2];

      float a0 = wvj[0] * (B0 * x0)
               + wvj[4] * (B4[0]*xa + B4[1]*xb + B4[2]*xc);
      float a1[3];
      #pragma unroll
      for (int c = 0; c < 3; ++c)
        a1[c] = wvj[1] * (B1[c] * x0)
              + wvj[3] * (B3[c]*xa + B3[3+c]*xb + B3[6+c]*xc)
              + wvj[5] * (B5[c]*xa + B5[3+c]*xb + B5[6+c]*xc)
              + wvj[7] * (B7[c]*xa + B7[3+c]*xb + B7[6+c]*xc);
      float a2[5];
      #pragma unroll
      for (int c = 0; c < 5; ++c)
        a2[c] = wvj[2] * (B2[c] * x0)
              + wvj[6] * (B6[c]*xa + B6[5+c]*xb + B6[10+c]*xc)
              + wvj[8] * (B8[c]*xa + B8[5+c]*xb + B8[10+c]*xc);

      SEGSUM(a0);
      #pragma unroll
      for (int c = 0; c < 3; ++c) SEGSUM(a1[c]);
      #pragma unroll
      for (int c = 0; c < 5; ++c) SEGSUM(a2[c]);

      if (tail){
        if (USE_ROWS){
          dstrow[u] = a0;
          #pragma unroll
          for (int c = 0; c < 3; ++c) dstrow[32 + 3*u + c] = a1[c];
          #pragma unroll
          for (int c = 0; c < 5; ++c) dstrow[128 + 5*u + c] = a2[c];
        } else {
          unsafeAtomicAdd(&dstrow[u], a0);
          #pragma unroll
          for (int c = 0; c < 3; ++c) unsafeAtomicAdd(&dstrow[32 + 3*u + c], a1[c]);
          #pragma unroll
          for (int c = 0; c < 5; ++c) unsafeAtomicAdd(&dstrow[128 + 5*u + c], a2[c]);
        }
      }
    }

    // ---- stage next W2 quarter (W2h unread in this epoch) ----
    if (h < 3){
      int qn = h + 1;
      #pragma unroll 1
      for (int m = 0; m < 20; ++m){
        int flat = m * TPB + tid;
        int col  = flat % QC;
        int k    = flat / QC;
        int p    = col >> 3, uu = col & 7;
        float v  = (p < 9) ? W2[k * 288 + p * 32 + qn * 8 + uu] : 0.f;
        W2h[col * WP + k] = f2bf(v);
      }
    }
  }
}

// ---------------- combine: block per dst, closed-form row range -------------
__global__ void combine_kernel(const float* __restrict__ rows,
                               const int* __restrict__ starts,
                               const int* __restrict__ nzrank,
                               float* __restrict__ out, int N)
{
  int d = blockIdx.x;
  if (d >= N) return;
  int c = threadIdx.x;   // 64
  int s0 = starts[d], s1 = starts[d + 1];
  float a0 = 0.f, a1 = 0.f, a2 = 0.f, a3 = 0.f, a4 = 0.f;
  if (s1 > s0){
    int r0 = nzrank[d] + (s0 >> 6);
    int r1 = nzrank[d] + ((s1 - 1) >> 6);
    for (int r = r0; r <= r1; ++r){
      const float* row = rows + (size_t)r * 288;
      a0 += row[c];
      a1 += row[c + 64];
      a2 += row[c + 128];
      a3 += row[c + 192];
      if (c < 32) a4 += row[c + 256];
    }
  }
  float* o = out + (size_t)d * 288;
  o[c] = a0; o[c + 64] = a1; o[c + 128] = a2; o[c + 192] = a3;
  if (c < 32) o[c + 256] = a4;
}

// fallback (atomic per edge) if ws too small for CSR arrays
__global__ void __launch_bounds__(TPB, 2) tfn_atomic_kernel(
    const float* __restrict__ nf, const float* __restrict__ ef,
    const float* __restrict__ ev, const int* __restrict__ ei,
    const float* __restrict__ W0, const float* __restrict__ W1,
    const float* __restrict__ W2, const float* __restrict__ cg,
    float* __restrict__ out, int E)
{
  int e = blockIdx.x * TPB + threadIdx.x;
  if (e >= E) return;

  float f0[16];
  #pragma unroll
  for (int q = 0; q < 16; ++q) f0[q] = ef[(size_t)e*16 + q];
  float h1[64];
  #pragma unroll
  for (int j = 0; j < 64; ++j) h1[j] = 0.f;
  for (int k = 0; k < 64; ++k){
    float a = 0.f;
    #pragma unroll
    for (int q = 0; q < 16; ++q) a += f0[q] * W0[q*64 + k];
    float g = silu_f(a);
    #pragma unroll
    for (int j = 0; j < 64; ++j) h1[j] += g * W1[k*64 + j];
  }
  #pragma unroll
  for (int j = 0; j < 64; ++j) h1[j] = silu_f(h1[j]);

  float ex = ev[(size_t)e*3+0], eyv = ev[(size_t)e*3+1], ezv = ev[(size_t)e*3+2];
  float ri = __builtin_amdgcn_rcpf(sqrtf(ex*ex + eyv*eyv + ezv*ezv) + 1e-12f);
  float X = ex*ri, Y = eyv*ri, Z = ezv*ri;
  const float s3 = 1.7320508075688772f;
  float Y1v[3] = {Y, Z, X};
  float Y2v[5] = {s3*X*Y, s3*Y*Z, 0.5f*(3.f*Z*Z - 1.f), s3*X*Z, 0.5f*s3*(X*X - Y*Y)};

  float B0 = cg[0];
  float B1[3], B2[5], B3[9], B4[3], B5[9], B6[15], B7[9], B8[15];
  #pragma unroll
  for (int c = 0; c < 3; ++c){ float s = 0.f;
    #pragma unroll
    for (int b = 0; b < 3; ++b) s += cg[1 + b*3 + c] * Y1v[b];
    B1[c] = s; }
  #pragma unroll
  for (int c = 0; c < 5; ++c){ float s = 0.f;
    #pragma unroll
    for (int b = 0; b < 5; ++b) s += cg[10 + b*5 + c] * Y2v[b];
    B2[c] = s; }
  #pragma unroll
  for (int i = 0; i < 9; ++i) B3[i] = cg[35 + i];
  #pragma unroll
  for (int a = 0; a < 3; ++a){ float s = 0.f;
    #pragma unroll
    for (int b = 0; b < 3; ++b) s += cg[44 + a*3 + b] * Y1v[b];
    B4[a] = s; }
  #pragma unroll
  for (int a = 0; a < 3; ++a)
    #pragma unroll
    for (int c = 0; c < 3; ++c){ float s = 0.f;
      #pragma unroll
      for (int b = 0; b < 3; ++b) s += cg[53 + (a*3 + b)*3 + c] * Y1v[b];
      B5[a*3 + c] = s; }
  #pragma unroll
  for (int a = 0; a < 3; ++a)
    #pragma unroll
    for (int c = 0; c < 5; ++c){ float s = 0.f;
      #pragma unroll
      for (int b = 0; b < 3; ++b) s += cg[80 + (a*3 + b)*5 + c] * Y1v[b];
      B6[a*5 + c] = s; }
  #pragma unroll
  for (int a = 0; a < 3; ++a)
    #pragma unroll
    for (int c = 0; c < 3; ++c){ float s = 0.f;
      #pragma unroll
      for (int b = 0; b < 5; ++b) s += cg[125 + (a*5 + b)*3 + c] * Y2v[b];
      B7[a*3 + c] = s; }
  #pragma unroll
  for (int a = 0; a < 3; ++a)
    #pragma unroll
    for (int c = 0; c < 5; ++c){ float s = 0.f;
      #pragma unroll
      for (int b = 0; b < 5; ++b) s += cg[170 + (a*5 + b)*5 + c] * Y2v[b];
      B8[a*5 + c] = s; }

  int src = ei[2*e], dst = ei[2*e + 1];
  const float* xr = nf + (size_t)src * 128;
  float* orow = out + (size_t)dst * 288;

  for (int u = 0; u < 32; ++u){
    float wv[9];
    #pragma unroll
    for (int p = 0; p < 9; ++p) wv[p] = 0.f;
    #pragma unroll
    for (int k = 0; k < 64; ++k){
      float hk = h1[k];
      #pragma unroll
      for (int p = 0; p < 9; ++p) wv[p] += hk * W2[k*288 + p*32 + u];
    }
    #pragma unroll
    for (int p = 0; p < 9; ++p) wv[p] = silu_f(wv[p]);

    float x0 = xr[u];
    float xa = xr[32 + 3*u + 0], xb = xr[32 + 3*u + 1], xc = xr[32 + 3*u + 2];

    float a0 = wv[0] * (B0 * x0)
             + wv[4] * (B4[0]*xa + B4[1]*xb + B4[2]*xc);
    float a1[3];
    #pragma unroll
    for (int c = 0; c < 3; ++c)
      a1[c] = wv[1] * (B1[c] * x0)
            + wv[3] * (B3[c]*xa + B3[3+c]*xb + B3[6+c]*xc)
            + wv[5] * (B5[c]*xa + B5[3+c]*xb + B5[6+c]*xc)
            + wv[7] * (B7[c]*xa + B7[3+c]*xb + B7[6+c]*xc);
    float a2[5];
    #pragma unroll
    for (int c = 0; c < 5; ++c)
      a2[c] = wv[2] * (B2[c] * x0)
            + wv[6] * (B6[c]*xa + B6[5+c]*xb + B6[10+c]*xc)
            + wv[8] * (B8[c]*xa + B8[5+c]*xb + B8[10+c]*xc);

    unsafeAtomicAdd(&orow[u], a0);
    #pragma unroll
    for (int c = 0; c < 3; ++c) unsafeAtomicAdd(&orow[32 + 3*u + c], a1[c]);
    #pragma unroll
    for (int c = 0; c < 5; ++c) unsafeAtomicAdd(&orow[128 + 5*u + c], a2[c]);
  }
}

extern "C" void kernel_launch(void* const* d_in, const int* in_sizes, int n_in,
                              void* d_out, int out_size, void* d_ws, size_t ws_size,
                              hipStream_t stream)
{
  const float* nf = (const float*)d_in[0];
  const float* ef = (const float*)d_in[1];
  const float* ev = (const float*)d_in[2];
  const int*   ei = (const int*)  d_in[3];
  const float* W0 = (const float*)d_in[4];
  const float* W1 = (const float*)d_in[5];
  const float* W2 = (const float*)d_in[6];
  float* out = (float*)d_out;

  int E = in_sizes[3] / 2;
  int N = in_sizes[0] / 128;
  int R = E / 64 + N + 64;           // bound on partial rows

  // ws layout (4-byte units)
  float* cg     = (float*)d_ws;                        // 256
  int*   counts = (int*)d_ws + 256;                    // N
  int*   starts = counts + N;                          // N+1
  int*   cursor = starts + N + 1;                      // N
  int*   nzrank = cursor + N;                          // N
  int*   perm   = nzrank + N;                          // E
  size_t base_off = (size_t)256 + 4*(size_t)N + 1 + E;
  size_t rows_off = (base_off + 3) & ~(size_t)3;
  float* rows   = (float*)d_ws + rows_off;

  size_t need_csr  = base_off * 4;
  size_t need_rows = (rows_off + (size_t)R * 288) * 4;

  int hb = (E + TPB - 1) / TPB;

  if (ws_size >= need_rows){
    hipMemsetAsync(counts, 0, (size_t)N * sizeof(int), stream);
    hist_cg_kernel<<<hb + 1, TPB, 0, stream>>>(ei, counts, E, cg, hb);
    scan_kernel<<<1, 1024, 0, stream>>>(counts, starts, cursor, nzrank, N);
    perm_kernel<<<hb, TPB, 0, stream>>>(ei, cursor, perm, E);
    tfn_mfma_kernel<true><<<(E + TE - 1) / TE, TPB, 0, stream>>>(
        nf, ef, ev, ei, W0, W1, W2, cg, perm, nzrank, rows, out, E);
    combine_kernel<<<N, 64, 0, stream>>>(rows, starts, nzrank, out, N);
  } else if (ws_size >= need_csr){
    hipMemsetAsync(d_out, 0, (size_t)out_size * sizeof(float), stream);
    hipMemsetAsync(counts, 0, (size_t)N * sizeof(int), stream);
    hist_cg_kernel<<<hb + 1, TPB, 0, stream>>>(ei, counts, E, cg, hb);
    scan_kernel<<<1, 1024, 0, stream>>>(counts, starts, cursor, nzrank, N);
    perm_kernel<<<hb, TPB, 0, stream>>>(ei, cursor, perm, E);
    tfn_mfma_kernel<false><<<(E + TE - 1) / TE, TPB, 0, stream>>>(
        nf, ef, ev, ei, W0, W1, W2, cg, perm, nzrank, rows, out, E);
  } else {
    hipMemsetAsync(d_out, 0, (size_t)out_size * sizeof(float), stream);
    cg_init_kernel<<<1, 256, 0, stream>>>(cg);
    tfn_atomic_kernel<<<hb, TPB, 0, stream>>>(nf, ef, ev, ei, W0, W1, W2, cg, out, E);
  }
}

// Round 3
// 349.375 us; speedup vs baseline: 1.6797x; 1.3590x over previous
//
#include <hip/hip_runtime.h>
#include <hip/hip_bf16.h>
#include <math.h>

#define TPB 256
#define TE  64
#define HP  72     // Hs / H0s / W1b ushort pitch (144 B row, 16B-aligned for b128)
#define EP  40     // EFs / W0b ushort pitch (80 B row, 16B-aligned)
#define WP  72     // W2h ushort pitch
#define CP  90     // Cs ushort pitch: 45 dwords (odd) -> phase-4 reads 2-way
#define QC  80     // staged cols per quarter (72 real + 8 zero)

// bf16 weight cache in ws (ushort units):
//   w0bf[64 cols][32 k]          = 2048   (k>=16 zero-padded)
//   w1bf[64 cols][64 k]          = 4096
//   w2bf[4 q][80 cols][64 k]     = 20480  (cols 72..79 zero)
#define WBF_USH 26624              // = 13312 dwords

typedef float  v4f __attribute__((ext_vector_type(4)));
typedef short  s8v __attribute__((ext_vector_type(8)));
typedef float  f4v __attribute__((ext_vector_type(4)));

// ---------------------------------------------------------------------------
// ws layout (4-byte units):
//   cg[256] | wbf[13312] | counts[N] | starts[N+1] | cursor[N] | nzrank[N]
//   | perm[E] | (align4) rows[R*288]
// ---------------------------------------------------------------------------

__device__ double dfact(int n){ double r = 1.0; for (int i = 2; i <= n; ++i) r *= (double)i; return r; }

__device__ void build_u(int l, double ur[5][5], double ui[5][5]){
  for (int i = 0; i < 5; ++i) for (int j = 0; j < 5; ++j){ ur[i][j] = 0.0; ui[i][j] = 0.0; }
  ur[l][l] = 1.0;
  double s = 1.0 / sqrt(2.0);
  for (int m = 1; m <= l; ++m){
    double sg = (m & 1) ? -1.0 : 1.0;
    ur[l + m][l + m] = sg * s;
    ur[l + m][l - m] = s;
    ui[l - m][l - m] = s;
    ui[l - m][l + m] = -sg * s;
  }
}

// One thread per CG output element (245). Re/im choice = parity rule.
__device__ void cg_compute(int tid, float* __restrict__ cg){
  if (tid >= 245) return;
  const int L1[9]  = {0,0,0,1,1,1,1,1,1};
  const int L2[9]  = {0,1,2,0,1,1,1,2,2};
  const int L3[9]  = {0,1,2,1,0,1,2,1,2};
  const int OFF[10] = {0,1,10,35,44,53,80,125,170,245};
  int p = 0;
  while (p < 8 && tid >= OFF[p+1]) ++p;
  int idx = tid - OFF[p];
  int l1 = L1[p], l2 = L2[p], l3 = L3[p];
  int n1 = 2*l1+1, n2 = 2*l2+1, n3 = 2*l3+1;
  int c = idx % n3; int ab = idx / n3; int b = ab % n2; int a = ab / n2;

  double Cc[5][5][5];
  for (int i = 0; i < 5; ++i) for (int j = 0; j < 5; ++j) for (int k = 0; k < 5; ++k) Cc[i][j][k] = 0.0;
  for (int m1 = -l1; m1 <= l1; ++m1) for (int m2 = -l2; m2 <= l2; ++m2){
    int m3 = m1 + m2;
    if (m3 < -l3 || m3 > l3) continue;
    double pref = sqrt((double)(2*l3+1) * dfact(l1+l2-l3) * dfact(l1-l2+l3) * dfact(-l1+l2+l3) / dfact(l1+l2+l3+1));
    pref *= sqrt(dfact(l3+m3)*dfact(l3-m3)*dfact(l1-m1)*dfact(l1+m1)*dfact(l2-m2)*dfact(l2+m2));
    double s = 0.0;
    for (int k = 0; k <= l1 + l2 - l3; ++k){
      int a0 = k, a1 = l1+l2-l3-k, a2 = l1-m1-k, a3 = l2+m2-k, a4 = l3-l2+m1+k, a5 = l3-l1-m2+k;
      if (a0 < 0 || a1 < 0 || a2 < 0 || a3 < 0 || a4 < 0 || a5 < 0) continue;
      double dd = dfact(a0)*dfact(a1)*dfact(a2)*dfact(a3)*dfact(a4)*dfact(a5);
      s += ((k & 1) ? -1.0 : 1.0) / dd;
    }
    Cc[m1+l1][m2+l2][m3+l3] = pref * s;
  }

  double U1r[5][5], U1i[5][5], U2r[5][5], U2i[5][5], U3r[5][5], U3i[5][5];
  build_u(l1, U1r, U1i); build_u(l2, U2r, U2i); build_u(l3, U3r, U3i);

  double sr = 0.0, si = 0.0;
  for (int m = 0; m < n1; ++m) for (int n = 0; n < n2; ++n) for (int o = 0; o < n3; ++o){
    double cc = Cc[m][n][o];
    if (cc == 0.0) continue;
    double xre = U1r[a][m], xim = U1i[a][m];
    double yre = U2r[b][n], yim = U2i[b][n];
    double zr = xre*yre - xim*yim, zi = xre*yim + xim*yre;
    double wr = U3r[c][o], wi = -U3i[c][o];
    double pr = zr*wr - zi*wi, pi = zr*wi + zi*wr;
    sr += pr * cc; si += pi * cc;
  }
  int use_re = (((l1 + l2 + l3) & 1) == 0);
  cg[tid] = (float)(use_re ? sr : si);
}

__global__ void cg_init_kernel(float* __restrict__ cg){
  cg_compute(threadIdx.x, cg);
}

// ---------------- helpers ----------------

__device__ __forceinline__ float silu_f(float x){
  float t = __expf(-x);
  return x * __builtin_amdgcn_rcpf(1.0f + t);
}

__device__ __forceinline__ ushort f2bf(float x){
  __hip_bfloat16 h = __float2bfloat16(x);   // RNE
  return *reinterpret_cast<ushort*>(&h);
}

__device__ __forceinline__ float bf2f(ushort u){
  uint v = (uint)u << 16;
  union { uint i; float f; } c; c.i = v;
  return c.f;
}

// ---------------- CSR build + bf16 weight conversion ----------------
// blocks [0,nb): edge histogram (2 edges/thread)
// block nb: CG table
// blocks (nb, nb+8]: convert W0/W1/W2 -> bf16 LDS-ready layouts in wbf

__global__ void hist_cg_kernel(const int* __restrict__ ei, int* __restrict__ counts,
                               int E, float* __restrict__ cg, int nb,
                               const float* __restrict__ W0, const float* __restrict__ W1,
                               const float* __restrict__ W2, ushort* __restrict__ wbf){
  int b = blockIdx.x;
  if (b >= nb){
    if (b == nb){ cg_compute(threadIdx.x, cg); return; }
    int gid = (b - nb - 1) * TPB + threadIdx.x;   // 0..2047
    #pragma unroll 1
    for (int j = 0; j < 13; ++j){
      int idx = j * 2048 + gid;                   // 0..26623
      if (idx < 2048){
        int col = idx >> 5, k = idx & 31;
        wbf[idx] = (k < 16) ? f2bf(W0[k*64 + col]) : (ushort)0;
      } else if (idx < 6144){
        int t2 = idx - 2048;
        int col = t2 >> 6, k = t2 & 63;
        wbf[idx] = f2bf(W1[k*64 + col]);
      } else {
        int t2 = idx - 6144;
        int qn = t2 / 5120, rem = t2 % 5120;
        int col = rem >> 6, k = rem & 63;
        int p = col >> 3, uu = col & 7;
        wbf[idx] = (p < 9) ? f2bf(W2[k*288 + p*32 + qn*8 + uu]) : (ushort)0;
      }
    }
    return;
  }
  int i = b * TPB + threadIdx.x;
  if (2*i + 1 < E){
    int4 v = ((const int4*)ei)[i];
    atomicAdd(&counts[v.y], 1);
    atomicAdd(&counts[v.w], 1);
  } else if (2*i < E){
    atomicAdd(&counts[ei[4*i + 1]], 1);
  }
}

__global__ void scan_kernel(const int* __restrict__ counts, int* __restrict__ starts,
                            int* __restrict__ cursor, int* __restrict__ nzrank, int N){
  __shared__ int part[1024];
  __shared__ int pnz[1024];
  int t = threadIdx.x;
  int T = (N + 1023) >> 10;
  int base = t * T;
  int s = 0, z = 0;
  for (int i = 0; i < T; ++i){
    int idx = base + i;
    if (idx < N){ int cc = counts[idx]; s += cc; z += (cc > 0); }
  }
  part[t] = s; pnz[t] = z; __syncthreads();
  for (int off = 1; off < 1024; off <<= 1){
    int v = (t >= off) ? part[t - off] : 0;
    int w = (t >= off) ? pnz[t - off] : 0;
    __syncthreads();
    part[t] += v; pnz[t] += w;
    __syncthreads();
  }
  int excl = (t == 0) ? 0 : part[t - 1];
  int enz  = (t == 0) ? 0 : pnz[t - 1];
  for (int i = 0; i < T; ++i){
    int idx = base + i;
    if (idx < N){
      starts[idx] = excl; cursor[idx] = excl; nzrank[idx] = enz;
      int cc = counts[idx];
      excl += cc; enz += (cc > 0);
    }
  }
  if (t == 1023) starts[N] = part[1023];
}

__global__ void perm_kernel(const int* __restrict__ ei, int* __restrict__ cursor,
                            int* __restrict__ perm, int E){
  int i = blockIdx.x * TPB + threadIdx.x;
  if (2*i + 1 < E){
    int4 v = ((const int4*)ei)[i];
    int p0 = atomicAdd(&cursor[v.y], 1); perm[p0] = 2*i;
    int p1 = atomicAdd(&cursor[v.w], 1); perm[p1] = 2*i + 1;
  } else if (2*i < E){
    int pos = atomicAdd(&cursor[ei[4*i + 1]], 1);
    perm[pos] = 2*i;
  }
}

// ---------------- DPP segmented scan (VALU-only, no DS) ----------------
// Canonical GCN wave64 scan: row_shr:1/2/4/8 (row-local, bound_ctrl 0-fill),
// then row_bcast15 with ROW_MASK 0xA (rows 1,3 receive) and row_bcast31 with
// ROW_MASK 0xC (rows 2,3 receive).  Segment gating: same DPP pattern applied
// to d (old = -2 never matches a real dst), masks precomputed once.

#define DPPF(x, ctrl, rmask) __int_as_float(__builtin_amdgcn_update_dpp(0, __float_as_int(x), ctrl, rmask, 0xF, true))
#define DPPI(x, ctrl, rmask) __builtin_amdgcn_update_dpp(-2, (x), ctrl, rmask, 0xF, false)

#define SEGSUM(v) { \
  v += m1f  * DPPF(v, 0x111, 0xF); \
  v += m2f  * DPPF(v, 0x112, 0xF); \
  v += m4f  * DPPF(v, 0x114, 0xF); \
  v += m8f  * DPPF(v, 0x118, 0xF); \
  v += m15f * DPPF(v, 0x142, 0xA); \
  v += m31f * DPPF(v, 0x143, 0xC); }

// ---------------------------------------------------------------------------
// Block-cooperative MFMA kernel. All three MLP GEMMs on the matrix pipe.
// Weights come pre-converted (wbf) in LDS-ready [col][k] bf16 layouts, so all
// LDS staging is linear coalesced b32 copies (bank-conflict-free, no cvt).
// Segmented scatter-sum uses the DPP wave64 segmented scan (no DS ops).
// ---------------------------------------------------------------------------
template<bool USE_ROWS>
__global__ void __launch_bounds__(TPB, 4) tfn_mfma_kernel(
    const float* __restrict__ nf, const float* __restrict__ ef,
    const float* __restrict__ ev, const int* __restrict__ ei,
    const ushort* __restrict__ wbf, const float* __restrict__ cg,
    const int* __restrict__ perm, const int* __restrict__ nzrank,
    float* __restrict__ rows, float* __restrict__ out, int E)
{
  // One 32256 B arena, aliased between prologue and main loop.
  //   main:     Hs[0,9216) | W2h[9216,20736) | Cs[20736,32256)
  //   prologue: EFs[0,5120) | W0b[5120,10240) | H0s[10240,19456) | W1b[19456,28672)
  __shared__ char ldsb[32256];
  ushort* Hs  = (ushort*)(ldsb);
  ushort* W2h = (ushort*)(ldsb + 9216);
  ushort* Cs  = (ushort*)(ldsb + 20736);
  ushort* EFs = (ushort*)(ldsb);
  ushort* W0b = (ushort*)(ldsb + 5120);
  ushort* H0s = (ushort*)(ldsb + 10240);
  ushort* W1b = (ushort*)(ldsb + 19456);

  const int tid  = threadIdx.x;
  const int el   = tid & 63;
  const int wq   = tid >> 6;
  const int lane = el;

  int t = blockIdx.x * TE + el;
  bool valid = (t < E);
  int e = perm[valid ? t : (E - 1)];
  int d = valid ? ei[2*e + 1] : -1;
  int src = ei[2*e];

  // segment masks (wave-constant per window, reused for all 72 SEGSUMs)
  float m1f  = (d == DPPI(d, 0x111, 0xF)) ? 1.f : 0.f;
  float m2f  = (d == DPPI(d, 0x112, 0xF)) ? 1.f : 0.f;
  float m4f  = (d == DPPI(d, 0x114, 0xF)) ? 1.f : 0.f;
  float m8f  = (d == DPPI(d, 0x118, 0xF)) ? 1.f : 0.f;
  float m15f = (d == DPPI(d, 0x142, 0xA)) ? 1.f : 0.f;
  float m31f = (d == DPPI(d, 0x143, 0xC)) ? 1.f : 0.f;

  int nd = __shfl_down(d, 1);
  bool tail = valid && ((lane == 63) || (nd != d));

  int ri = 0;
  if (USE_ROWS) ri = (d >= 0 ? nzrank[d] : 0) + (t >> 6);

  const uint* wbu = (const uint*)wbf;   // w0:[0,1024) w1:[1024,3072) w2:[3072,13312)

  // ================= Prologue staging (linear b32 copies) =================
  {
    // ef tile: thread (el,wq) stages its 4-float quarter; pad k 16..32 = 0
    const v4f efv = *(const v4f*)(ef + (size_t)e * 16 + wq * 4);
    uint p0 = (uint)f2bf(efv.x) | ((uint)f2bf(efv.y) << 16);
    uint p1 = (uint)f2bf(efv.z) | ((uint)f2bf(efv.w) << 16);
    *(uint*)&EFs[el * EP + wq * 4]          = p0;
    *(uint*)&EFs[el * EP + wq * 4 + 2]      = p1;
    *(uint*)&EFs[el * EP + 16 + wq * 4]     = 0u;
    *(uint*)&EFs[el * EP + 16 + wq * 4 + 2] = 0u;
  }
  {
    // W0b: 1024 uints, rows of 16 uints -> LDS pitch 20 uints
    const uint* g0 = wbu + tid;
    uint* W0w = (uint*)W0b;
    const int bb = (tid >> 4) * 20 + (tid & 15);
    #pragma unroll
    for (int i = 0; i < 4; ++i) W0w[bb + i*320] = g0[i*256];
  }
  {
    // W1b: 2048 uints, rows of 32 -> pitch 36
    const uint* g1 = wbu + 1024 + tid;
    uint* W1w = (uint*)W1b;
    const int b1 = (tid >> 5) * 36 + (tid & 31);
    #pragma unroll
    for (int i = 0; i < 8; ++i) W1w[b1 + i*288] = g1[i*256];
  }
  __syncthreads();

  const int r = lane & 15, q = lane >> 4;
  const int rowbase = wq * 16;

  // ---- layer 0 on MFMA: (64x16 ef) @ (16x64 W0), K zero-padded to 32 ----
  {
    s8v a = *(const s8v*)&EFs[(rowbase + r) * EP + q * 8];
    #pragma unroll
    for (int tt = 0; tt < 4; ++tt){
      f4v acc = {0.f, 0.f, 0.f, 0.f};
      s8v b = *(const s8v*)&W0b[(tt*16 + r) * EP + q * 8];
      acc = __builtin_amdgcn_mfma_f32_16x16x32_bf16(a, b, acc, 0, 0, 0);
      #pragma unroll
      for (int rr = 0; rr < 4; ++rr)
        H0s[(rowbase + q*4 + rr) * HP + tt*16 + r] = f2bf(silu_f(acc[rr]));
    }
  }
  __syncthreads();

  // ---- layer 1 on MFMA: (64x64 H0) @ (64x64 W1) ----
  {
    s8v a0 = *(const s8v*)&H0s[(rowbase + r) * HP + q * 8];
    s8v a1 = *(const s8v*)&H0s[(rowbase + r) * HP + 32 + q * 8];
    #pragma unroll
    for (int tt = 0; tt < 4; ++tt){
      f4v acc = {0.f, 0.f, 0.f, 0.f};
      s8v b0 = *(const s8v*)&W1b[(tt*16 + r) * HP + q * 8];
      s8v b1 = *(const s8v*)&W1b[(tt*16 + r) * HP + 32 + q * 8];
      acc = __builtin_amdgcn_mfma_f32_16x16x32_bf16(a0, b0, acc, 0, 0, 0);
      acc = __builtin_amdgcn_mfma_f32_16x16x32_bf16(a1, b1, acc, 0, 0, 0);
      #pragma unroll
      for (int rr = 0; rr < 4; ++rr)
        Hs[(rowbase + q*4 + rr) * HP + tt*16 + r] = f2bf(silu_f(acc[rr]));
    }
  }
  __syncthreads();

  // ---- stage W2 quarter 0 (region now dead): linear b32 copy ----
  uint* W2w = (uint*)W2h;
  const int b2 = (tid >> 5) * 36 + (tid & 31);
  {
    const uint* gq = wbu + 3072 + tid;
    #pragma unroll
    for (int m = 0; m < 10; ++m) W2w[b2 + m*288] = gq[m*256];
  }

  // ---- spherical harmonics + Y-contracted CG ----
  float ex = ev[(size_t)e*3+0], eyv = ev[(size_t)e*3+1], ezv = ev[(size_t)e*3+2];
  float ri2 = __builtin_amdgcn_rcpf(sqrtf(ex*ex + eyv*eyv + ezv*ezv) + 1e-12f);
  float X = ex*ri2, Y = eyv*ri2, Z = ezv*ri2;
  const float s3 = 1.7320508075688772f;
  float Y1v[3] = {Y, Z, X};
  float Y2v[5] = {s3*X*Y, s3*Y*Z, 0.5f*(3.f*Z*Z - 1.f), s3*X*Z, 0.5f*s3*(X*X - Y*Y)};

  float B0 = cg[0];
  float B1[3], B2[5], B3[9], B4[3], B5[9], B6[15], B7[9], B8[15];
  #pragma unroll
  for (int c = 0; c < 3; ++c){ float s = 0.f;
    #pragma unroll
    for (int b = 0; b < 3; ++b) s += cg[1 + b*3 + c] * Y1v[b];
    B1[c] = s; }
  #pragma unroll
  for (int c = 0; c < 5; ++c){ float s = 0.f;
    #pragma unroll
    for (int b = 0; b < 5; ++b) s += cg[10 + b*5 + c] * Y2v[b];
    B2[c] = s; }
  #pragma unroll
  for (int i = 0; i < 9; ++i) B3[i] = cg[35 + i];
  #pragma unroll
  for (int a = 0; a < 3; ++a){ float s = 0.f;
    #pragma unroll
    for (int b = 0; b < 3; ++b) s += cg[44 + a*3 + b] * Y1v[b];
    B4[a] = s; }
  #pragma unroll
  for (int a = 0; a < 3; ++a)
    #pragma unroll
    for (int c = 0; c < 3; ++c){ float s = 0.f;
      #pragma unroll
      for (int b = 0; b < 3; ++b) s += cg[53 + (a*3 + b)*3 + c] * Y1v[b];
      B5[a*3 + c] = s; }
  #pragma unroll
  for (int a = 0; a < 3; ++a)
    #pragma unroll
    for (int c = 0; c < 5; ++c){ float s = 0.f;
      #pragma unroll
      for (int b = 0; b < 3; ++b) s += cg[80 + (a*3 + b)*5 + c] * Y1v[b];
      B6[a*5 + c] = s; }
  #pragma unroll
  for (int a = 0; a < 3; ++a)
    #pragma unroll
    for (int c = 0; c < 3; ++c){ float s = 0.f;
      #pragma unroll
      for (int b = 0; b < 5; ++b) s += cg[125 + (a*5 + b)*3 + c] * Y2v[b];
      B7[a*3 + c] = s; }
  #pragma unroll
  for (int a = 0; a < 3; ++a)
    #pragma unroll
    for (int c = 0; c < 5; ++c){ float s = 0.f;
      #pragma unroll
      for (int b = 0; b < 5; ++b) s += cg[170 + (a*5 + b)*5 + c] * Y2v[b];
      B8[a*5 + c] = s; }

  const float* xr = nf + (size_t)src * 128;
  float* dstrow = USE_ROWS ? (rows + (size_t)ri * 288)
                           : (out + (size_t)(d < 0 ? 0 : d) * 288);

  #pragma unroll 1
  for (int h = 0; h < 4; ++h){
    // issue this h's node-feature loads early (hidden under barrier+MFMA)
    int u0 = h*8 + wq*2;
    float2 x0p = *(const float2*)(xr + u0);
    float2 xq0 = *(const float2*)(xr + 32 + 3*u0);
    float2 xq1 = *(const float2*)(xr + 32 + 3*u0 + 2);
    float2 xq2 = *(const float2*)(xr + 32 + 3*u0 + 4);

    __syncthreads();   // W2h(quarter h) ready; Cs consumed

    // ============== MFMA: 5 col-tiles x 2 k-steps ==============
    s8v ha0 = *(const s8v*)&Hs[(rowbase + r) * HP + q * 8];
    s8v ha1 = *(const s8v*)&Hs[(rowbase + r) * HP + 32 + q * 8];
    #pragma unroll 1
    for (int tt = 0; tt < 5; ++tt){
      f4v acc4 = {0.f, 0.f, 0.f, 0.f};
      s8v b0 = *(const s8v*)&W2h[(tt*16 + r) * WP + q * 8];
      s8v b1 = *(const s8v*)&W2h[(tt*16 + r) * WP + 32 + q * 8];
      acc4 = __builtin_amdgcn_mfma_f32_16x16x32_bf16(ha0, b0, acc4, 0, 0, 0);
      acc4 = __builtin_amdgcn_mfma_f32_16x16x32_bf16(ha1, b1, acc4, 0, 0, 0);
      #pragma unroll
      for (int rr = 0; rr < 4; ++rr)
        Cs[(rowbase + q*4 + rr) * CP + tt*16 + r] = f2bf(acc4[rr]);
    }

    __syncthreads();   // Cs ready; W2h consumed

    // ============== Phase 4: silu + tensor + segmented scatter ==============
    #pragma unroll
    for (int j = 0; j < 2; ++j){
      int uuq = wq * 2 + j;        // 0..7 within quarter
      int u   = h * 8 + uuq;       // global channel

      float wvj[9];
      #pragma unroll
      for (int p = 0; p < 9; ++p) wvj[p] = silu_f(bf2f(Cs[el * CP + p*8 + uuq]));

      float x0 = (j == 0) ? x0p.x : x0p.y;
      float xa = (j == 0) ? xq0.x : xq1.y;
      float xb = (j == 0) ? xq0.y : xq2.x;
      float xc = (j == 0) ? xq1.x : xq2.y;

      float a0 = wvj[0] * (B0 * x0)
               + wvj[4] * (B4[0]*xa + B4[1]*xb + B4[2]*xc);
      float a1[3];
      #pragma unroll
      for (int c = 0; c < 3; ++c)
        a1[c] = wvj[1] * (B1[c] * x0)
              + wvj[3] * (B3[c]*xa + B3[3+c]*xb + B3[6+c]*xc)
              + wvj[5] * (B5[c]*xa + B5[3+c]*xb + B5[6+c]*xc)
              + wvj[7] * (B7[c]*xa + B7[3+c]*xb + B7[6+c]*xc);
      float a2[5];
      #pragma unroll
      for (int c = 0; c < 5; ++c)
        a2[c] = wvj[2] * (B2[c] * x0)
              + wvj[6] * (B6[c]*xa + B6[5+c]*xb + B6[10+c]*xc)
              + wvj[8] * (B8[c]*xa + B8[5+c]*xb + B8[10+c]*xc);

      SEGSUM(a0);
      #pragma unroll
      for (int c = 0; c < 3; ++c) SEGSUM(a1[c]);
      #pragma unroll
      for (int c = 0; c < 5; ++c) SEGSUM(a2[c]);

      if (tail){
        if (USE_ROWS){
          dstrow[u] = a0;
          #pragma unroll
          for (int c = 0; c < 3; ++c) dstrow[32 + 3*u + c] = a1[c];
          #pragma unroll
          for (int c = 0; c < 5; ++c) dstrow[128 + 5*u + c] = a2[c];
        } else {
          unsafeAtomicAdd(&dstrow[u], a0);
          #pragma unroll
          for (int c = 0; c < 3; ++c) unsafeAtomicAdd(&dstrow[32 + 3*u + c], a1[c]);
          #pragma unroll
          for (int c = 0; c < 5; ++c) unsafeAtomicAdd(&dstrow[128 + 5*u + c], a2[c]);
        }
      }
    }

    // ---- stage next W2 quarter (W2h unread in this epoch): linear copy ----
    if (h < 3){
      const uint* gq = wbu + 3072 + (h+1)*2560 + tid;
      #pragma unroll
      for (int m = 0; m < 10; ++m) W2w[b2 + m*288] = gq[m*256];
    }
  }
}

// ---------------- combine: 4 dsts per block ----------------
__global__ void combine_kernel(const float* __restrict__ rows,
                               const int* __restrict__ starts,
                               const int* __restrict__ nzrank,
                               float* __restrict__ out, int N)
{
  int g = threadIdx.x >> 6;
  int c = threadIdx.x & 63;
  int d = blockIdx.x * 4 + g;
  if (d >= N) return;
  int s0 = starts[d], s1 = starts[d + 1];
  float a0 = 0.f, a1 = 0.f, a2 = 0.f, a3 = 0.f, a4 = 0.f;
  if (s1 > s0){
    int r0 = nzrank[d] + (s0 >> 6);
    int r1 = nzrank[d] + ((s1 - 1) >> 6);
    for (int r = r0; r <= r1; ++r){
      const float* row = rows + (size_t)r * 288;
      a0 += row[c];
      a1 += row[c + 64];
      a2 += row[c + 128];
      a3 += row[c + 192];
      if (c < 32) a4 += row[c + 256];
    }
  }
  float* o = out + (size_t)d * 288;
  o[c] = a0; o[c + 64] = a1; o[c + 128] = a2; o[c + 192] = a3;
  if (c < 32) o[c + 256] = a4;
}

// fallback (atomic per edge) if ws too small for CSR arrays
__global__ void __launch_bounds__(TPB, 2) tfn_atomic_kernel(
    const float* __restrict__ nf, const float* __restrict__ ef,
    const float* __restrict__ ev, const int* __restrict__ ei,
    const float* __restrict__ W0, const float* __restrict__ W1,
    const float* __restrict__ W2, const float* __restrict__ cg,
    float* __restrict__ out, int E)
{
  int e = blockIdx.x * TPB + threadIdx.x;
  if (e >= E) return;

  float f0[16];
  #pragma unroll
  for (int q = 0; q < 16; ++q) f0[q] = ef[(size_t)e*16 + q];
  float h1[64];
  #pragma unroll
  for (int j = 0; j < 64; ++j) h1[j] = 0.f;
  for (int k = 0; k < 64; ++k){
    float a = 0.f;
    #pragma unroll
    for (int q = 0; q < 16; ++q) a += f0[q] * W0[q*64 + k];
    float g = silu_f(a);
    #pragma unroll
    for (int j = 0; j < 64; ++j) h1[j] += g * W1[k*64 + j];
  }
  #pragma unroll
  for (int j = 0; j < 64; ++j) h1[j] = silu_f(h1[j]);

  float ex = ev[(size_t)e*3+0], eyv = ev[(size_t)e*3+1], ezv = ev[(size_t)e*3+2];
  float ri = __builtin_amdgcn_rcpf(sqrtf(ex*ex + eyv*eyv + ezv*ezv) + 1e-12f);
  float X = ex*ri, Y = eyv*ri, Z = ezv*ri;
  const float s3 = 1.7320508075688772f;
  float Y1v[3] = {Y, Z, X};
  float Y2v[5] = {s3*X*Y, s3*Y*Z, 0.5f*(3.f*Z*Z - 1.f), s3*X*Z, 0.5f*s3*(X*X - Y*Y)};

  float B0 = cg[0];
  float B1[3], B2[5], B3[9], B4[3], B5[9], B6[15], B7[9], B8[15];
  #pragma unroll
  for (int c = 0; c < 3; ++c){ float s = 0.f;
    #pragma unroll
    for (int b = 0; b < 3; ++b) s += cg[1 + b*3 + c] * Y1v[b];
    B1[c] = s; }
  #pragma unroll
  for (int c = 0; c < 5; ++c){ float s = 0.f;
    #pragma unroll
    for (int b = 0; b < 5; ++b) s += cg[10 + b*5 + c] * Y2v[b];
    B2[c] = s; }
  #pragma unroll
  for (int i = 0; i < 9; ++i) B3[i] = cg[35 + i];
  #pragma unroll
  for (int a = 0; a < 3; ++a){ float s = 0.f;
    #pragma unroll
    for (int b = 0; b < 3; ++b) s += cg[44 + a*3 + b] * Y1v[b];
    B4[a] = s; }
  #pragma unroll
  for (int a = 0; a < 3; ++a)
    #pragma unroll
    for (int c = 0; c < 3; ++c){ float s = 0.f;
      #pragma unroll
      for (int b = 0; b < 3; ++b) s += cg[53 + (a*3 + b)*3 + c] * Y1v[b];
      B5[a*3 + c] = s; }
  #pragma unroll
  for (int a = 0; a < 3; ++a)
    #pragma unroll
    for (int c = 0; c < 5; ++c){ float s = 0.f;
      #pragma unroll
      for (int b = 0; b < 3; ++b) s += cg[80 + (a*3 + b)*5 + c] * Y1v[b];
      B6[a*5 + c] = s; }
  #pragma unroll
  for (int a = 0; a < 3; ++a)
    #pragma unroll
    for (int c = 0; c < 3; ++c){ float s = 0.f;
      #pragma unroll
      for (int b = 0; b < 5; ++b) s += cg[125 + (a*5 + b)*3 + c] * Y2v[b];
      B7[a*3 + c] = s; }
  #pragma unroll
  for (int a = 0; a < 3; ++a)
    #pragma unroll
    for (int c = 0; c < 5; ++c){ float s = 0.f;
      #pragma unroll
      for (int b = 0; b < 5; ++b) s += cg[170 + (a*5 + b)*5 + c] * Y2v[b];
      B8[a*5 + c] = s; }

  int src = ei[2*e], dst = ei[2*e + 1];
  const float* xr = nf + (size_t)src * 128;
  float* orow = out + (size_t)dst * 288;

  for (int u = 0; u < 32; ++u){
    float wv[9];
    #pragma unroll
    for (int p = 0; p < 9; ++p) wv[p] = 0.f;
    #pragma unroll
    for (int k = 0; k < 64; ++k){
      float hk = h1[k];
      #pragma unroll
      for (int p = 0; p < 9; ++p) wv[p] += hk * W2[k*288 + p*32 + u];
    }
    #pragma unroll
    for (int p = 0; p < 9; ++p) wv[p] = silu_f(wv[p]);

    float x0 = xr[u];
    float xa = xr[32 + 3*u + 0], xb = xr[32 + 3*u + 1], xc = xr[32 + 3*u + 2];

    float a0 = wv[0] * (B0 * x0)
             + wv[4] * (B4[0]*xa + B4[1]*xb + B4[2]*xc);
    float a1[3];
    #pragma unroll
    for (int c = 0; c < 3; ++c)
      a1[c] = wv[1] * (B1[c] * x0)
            + wv[3] * (B3[c]*xa + B3[3+c]*xb + B3[6+c]*xc)
            + wv[5] * (B5[c]*xa + B5[3+c]*xb + B5[6+c]*xc)
            + wv[7] * (B7[c]*xa + B7[3+c]*xb + B7[6+c]*xc);
    float a2[5];
    #pragma unroll
    for (int c = 0; c < 5; ++c)
      a2[c] = wv[2] * (B2[c] * x0)
            + wv[6] * (B6[c]*xa + B6[5+c]*xb + B6[10+c]*xc)
            + wv[8] * (B8[c]*xa + B8[5+c]*xb + B8[10+c]*xc);

    unsafeAtomicAdd(&orow[u], a0);
    #pragma unroll
    for (int c = 0; c < 3; ++c) unsafeAtomicAdd(&orow[32 + 3*u + c], a1[c]);
    #pragma unroll
    for (int c = 0; c < 5; ++c) unsafeAtomicAdd(&orow[128 + 5*u + c], a2[c]);
  }
}

extern "C" void kernel_launch(void* const* d_in, const int* in_sizes, int n_in,
                              void* d_out, int out_size, void* d_ws, size_t ws_size,
                              hipStream_t stream)
{
  const float* nf = (const float*)d_in[0];
  const float* ef = (const float*)d_in[1];
  const float* ev = (const float*)d_in[2];
  const int*   ei = (const int*)  d_in[3];
  const float* W0 = (const float*)d_in[4];
  const float* W1 = (const float*)d_in[5];
  const float* W2 = (const float*)d_in[6];
  float* out = (float*)d_out;

  int E = in_sizes[3] / 2;
  int N = in_sizes[0] / 128;
  int R = E / 64 + N + 64;           // bound on partial rows

  // ws layout (4-byte units)
  float*  cg     = (float*)d_ws;                       // 256
  ushort* wbf    = (ushort*)((float*)d_ws + 256);      // 26624 ushorts = 13312 dw
  int*    counts = (int*)d_ws + 256 + 13312;           // N
  int*    starts = counts + N;                         // N+1
  int*    cursor = starts + N + 1;                     // N
  int*    nzrank = cursor + N;                         // N
  int*    perm   = nzrank + N;                         // E
  size_t base_off = (size_t)256 + 13312 + 4*(size_t)N + 1 + E;
  size_t rows_off = (base_off + 3) & ~(size_t)3;
  float* rows   = (float*)d_ws + rows_off;

  size_t need_csr  = base_off * 4;
  size_t need_rows = (rows_off + (size_t)R * 288) * 4;

  int hb  = (E + TPB - 1) / TPB;             // for atomic fallback
  int hbv = (E/2 + TPB - 1) / TPB;           // 2 edges/thread

  if (ws_size >= need_rows){
    hipMemsetAsync(counts, 0, (size_t)N * sizeof(int), stream);
    hist_cg_kernel<<<hbv + 9, TPB, 0, stream>>>(ei, counts, E, cg, hbv, W0, W1, W2, wbf);
    scan_kernel<<<1, 1024, 0, stream>>>(counts, starts, cursor, nzrank, N);
    perm_kernel<<<hbv, TPB, 0, stream>>>(ei, cursor, perm, E);
    tfn_mfma_kernel<true><<<(E + TE - 1) / TE, TPB, 0, stream>>>(
        nf, ef, ev, ei, wbf, cg, perm, nzrank, rows, out, E);
    combine_kernel<<<(N + 3) / 4, TPB, 0, stream>>>(rows, starts, nzrank, out, N);
  } else if (ws_size >= need_csr){
    hipMemsetAsync(d_out, 0, (size_t)out_size * sizeof(float), stream);
    hipMemsetAsync(counts, 0, (size_t)N * sizeof(int), stream);
    hist_cg_kernel<<<hbv + 9, TPB, 0, stream>>>(ei, counts, E, cg, hbv, W0, W1, W2, wbf);
    scan_kernel<<<1, 1024, 0, stream>>>(counts, starts, cursor, nzrank, N);
    perm_kernel<<<hbv, TPB, 0, stream>>>(ei, cursor, perm, E);
    tfn_mfma_kernel<false><<<(E + TE - 1) / TE, TPB, 0, stream>>>(
        nf, ef, ev, ei, wbf, cg, perm, nzrank, rows, out, E);
  } else {
    hipMemsetAsync(d_out, 0, (size_t)out_size * sizeof(float), stream);
    cg_init_kernel<<<1, 256, 0, stream>>>(cg);
    tfn_atomic_kernel<<<hb, TPB, 0, stream>>>(nf, ef, ev, ei, W0, W1, W2, cg, out, E);
  }
}